// Round 1
// baseline (138.857 us; speedup 1.0000x reference)
//
#include <hip/hip_runtime.h>

#define NTOK 2048
#define IN_DIM 1024
#define OUT_DIM 512
#define RNK 32
#define TG_N 32
#define TGK_N 128
#define AWCOLS 4096
#define KD 4224          // 4096 affine_w cols + 128 bias-indicator cols
#define SCALE_F 0.17677669529663687f
#define LDK 72           // padded LDS row stride (bf16 elems): 144 B -> 4-bank step

typedef __attribute__((ext_vector_type(8))) short short8;
typedef __attribute__((ext_vector_type(4))) float float4v;

__device__ __forceinline__ unsigned short f2bf(float f) {
  union { float f; unsigned int u; } c; c.f = f;
  unsigned int u = c.u;
  u += 0x7fffu + ((u >> 16) & 1u);   // round-to-nearest-even
  return (unsigned short)(u >> 16);
}

// Kernel 1: per-token z (R=32), scores (T*G*K=128), argmin winner per (t,g),
// then emit the token's Z_exp row (4224 bf16).
__global__ __launch_bounds__(256) void k_tok(
    const float* __restrict__ x, const float* __restrict__ proj_w,
    const float* __restrict__ router_w, const float* __restrict__ router_b,
    unsigned short* __restrict__ zexp) {
  const int tok = blockIdx.x;
  const int t = threadIdx.x;
  __shared__ __align__(16) float zbuf[RNK];
  __shared__ float sc[TGK_N];
  __shared__ int winbuf[TG_N];

  // z[r] = dot(x[tok], proj_w[r]): thread (r = t>>3, c = t&7), shfl-reduce over 8 lanes
  const int r = t >> 3, c = t & 7;
  const float4* x4 = (const float4*)(x + (size_t)tok * IN_DIM);
  const float4* w4 = (const float4*)(proj_w + (size_t)r * IN_DIM);
  float acc = 0.f;
#pragma unroll
  for (int jj = 0; jj < 32; ++jj) {
    float4 xv = x4[jj * 8 + c];
    float4 wv = w4[jj * 8 + c];
    acc += xv.x * wv.x + xv.y * wv.y + xv.z * wv.z + xv.w * wv.w;
  }
  acc += __shfl_xor(acc, 1);
  acc += __shfl_xor(acc, 2);
  acc += __shfl_xor(acc, 4);
  if (c == 0) zbuf[r] = acc;
  __syncthreads();

  // scores for the 128 (t,g,k) cells
  if (t < TGK_N) {
    const float4* rw = (const float4*)(router_w + (size_t)t * RNK);
    const float4* zb = (const float4*)zbuf;
    float s = router_b[t];
#pragma unroll
    for (int j = 0; j < 8; ++j) {
      float4 a = rw[j]; float4 b = zb[j];
      s += a.x * b.x + a.y * b.y + a.z * b.z + a.w * b.w;
    }
    sc[t] = s;
  }
  __syncthreads();

  // first-min argmin over K=4 (strict < keeps first occurrence, matches jnp.argmin)
  if (t < TG_N) {
    float best = sc[t * 4]; int w = 0;
#pragma unroll
    for (int k = 1; k < 4; ++k) {
      float v = sc[t * 4 + k];
      if (v < best) { best = v; w = k; }
    }
    winbuf[t] = w;
  }
  __syncthreads();

  // Z_exp row: cols 0..4095 = masked z replicas; cols 4096..4223 = bias indicators
  unsigned short* zrow = zexp + (size_t)tok * KD;
  for (int e = t; e < KD; e += 256) {
    float v;
    if (e < AWCOLS) {
      int tg = e >> 7, k = (e >> 5) & 3, rr = e & 31;
      v = (winbuf[tg] == k) ? zbuf[rr] : 0.f;
    } else {
      int cb = e - AWCOLS; int tg = cb >> 2, k = cb & 3;
      v = (winbuf[tg] == k) ? 1.f : 0.f;
    }
    zrow[e] = f2bf(v);
  }
}

// Kernel 2: build W2t (OUT_DIM x KD bf16) = [affine_w ; affine_b] cast + transposed
// so the GEMM B operand is k-contiguous (no LDS transpose in the hot loop).
__global__ __launch_bounds__(256) void k_w2t(
    const float* __restrict__ aw, const float* __restrict__ ab,
    unsigned short* __restrict__ w2t) {
  __shared__ float tile[32][33];
  const int c0 = blockIdx.x * 32, o0 = blockIdx.y * 32;
  const int oo = threadIdx.x & 31, cc = threadIdx.x >> 5;  // cc 0..7
#pragma unroll
  for (int p = 0; p < 4; ++p) {
    int cidx = c0 + cc + p * 8;
    float v = (cidx < AWCOLS)
                  ? aw[(size_t)cidx * OUT_DIM + o0 + oo]
                  : ab[(size_t)(cidx - AWCOLS) * OUT_DIM + o0 + oo];
    tile[cc + p * 8][oo] = v;
  }
  __syncthreads();
  const int cc2 = threadIdx.x & 31, oo2 = threadIdx.x >> 5;
#pragma unroll
  for (int p = 0; p < 4; ++p) {
    int o = o0 + oo2 + p * 8;
    w2t[(size_t)o * KD + c0 + cc2] = f2bf(tile[cc2][oo2 + p * 8]);
  }
}

// Kernel 3: C(2048x512) = Zexp(2048xKD) @ W2t(512xKD)^T, fp32 acc, *SCALE epilogue.
// 64x64 block tile, BK=64, 4 waves as 2x2 of 32x32 (each: 2x2 MFMA 16x16x32 tiles).
__global__ __launch_bounds__(256) void k_gemm(
    const unsigned short* __restrict__ A, const unsigned short* __restrict__ Bt,
    float* __restrict__ out) {
  __shared__ __align__(16) unsigned short As[64 * LDK];
  __shared__ __align__(16) unsigned short Bs[64 * LDK];
  const int bm = blockIdx.x, bn = blockIdx.y;
  const int tid = threadIdx.x;
  const int wave = tid >> 6, lane = tid & 63;
  const int l15 = lane & 15, quad = lane >> 4;
  const int mw = (wave & 1) * 32, nw = (wave >> 1) * 32;
  float4v accs[2][2] = {};

  const int srow = tid >> 3;  // 0..31 (+32 on second pass)
  const int sch = tid & 7;    // 8 chunks of 8 bf16 = 64 cols
  const unsigned short* Ag = A + (size_t)(bm * 64) * KD;
  const unsigned short* Bg = Bt + (size_t)(bn * 64) * KD;

  for (int kt = 0; kt < KD / 64; ++kt) {
    const int k0 = kt * 64;
#pragma unroll
    for (int p = 0; p < 2; ++p) {
      int row = srow + p * 32;
      uint4 av = *(const uint4*)(Ag + (size_t)row * KD + k0 + sch * 8);
      *(uint4*)(&As[row * LDK + sch * 8]) = av;
      uint4 bv = *(const uint4*)(Bg + (size_t)row * KD + k0 + sch * 8);
      *(uint4*)(&Bs[row * LDK + sch * 8]) = bv;
    }
    __syncthreads();
#pragma unroll
    for (int s = 0; s < 2; ++s) {
      // A frag: A[m = lane&15][k = quad*8+j]; B frag: B[k = quad*8+j][n = lane&15]
      short8 a0 = *(const short8*)(&As[(mw + l15) * LDK + s * 32 + quad * 8]);
      short8 a1 = *(const short8*)(&As[(mw + 16 + l15) * LDK + s * 32 + quad * 8]);
      short8 b0 = *(const short8*)(&Bs[(nw + l15) * LDK + s * 32 + quad * 8]);
      short8 b1 = *(const short8*)(&Bs[(nw + 16 + l15) * LDK + s * 32 + quad * 8]);
      accs[0][0] = __builtin_amdgcn_mfma_f32_16x16x32_bf16(a0, b0, accs[0][0], 0, 0, 0);
      accs[0][1] = __builtin_amdgcn_mfma_f32_16x16x32_bf16(a0, b1, accs[0][1], 0, 0, 0);
      accs[1][0] = __builtin_amdgcn_mfma_f32_16x16x32_bf16(a1, b0, accs[1][0], 0, 0, 0);
      accs[1][1] = __builtin_amdgcn_mfma_f32_16x16x32_bf16(a1, b1, accs[1][1], 0, 0, 0);
    }
    __syncthreads();
  }

  // epilogue: C/D layout col = lane&15, row = quad*4 + reg
#pragma unroll
  for (int tm = 0; tm < 2; ++tm) {
#pragma unroll
    for (int tn = 0; tn < 2; ++tn) {
      int col = bn * 64 + nw + tn * 16 + l15;
#pragma unroll
      for (int rg = 0; rg < 4; ++rg) {
        int row = bm * 64 + mw + tm * 16 + quad * 4 + rg;
        out[(size_t)row * OUT_DIM + col] = accs[tm][tn][rg] * SCALE_F;
      }
    }
  }
}

extern "C" void kernel_launch(void* const* d_in, const int* in_sizes, int n_in,
                              void* d_out, int out_size, void* d_ws, size_t ws_size,
                              hipStream_t stream) {
  const float* x        = (const float*)d_in[0];
  const float* proj_w   = (const float*)d_in[1];
  const float* router_w = (const float*)d_in[2];
  const float* router_b = (const float*)d_in[3];
  const float* affine_w = (const float*)d_in[4];
  const float* affine_b = (const float*)d_in[5];
  float* out = (float*)d_out;

  unsigned short* zexp = (unsigned short*)d_ws;               // NTOK*KD bf16
  unsigned short* w2t  = zexp + (size_t)NTOK * KD;            // OUT_DIM*KD bf16

  k_w2t<<<dim3(KD / 32, OUT_DIM / 32), 256, 0, stream>>>(affine_w, affine_b, w2t);
  k_tok<<<NTOK, 256, 0, stream>>>(x, proj_w, router_w, router_b, zexp);
  k_gemm<<<dim3(NTOK / 64, OUT_DIM / 64), 256, 0, stream>>>(zexp, w2t, out);
}

// Round 2
// 110.907 us; speedup vs baseline: 1.2520x; 1.2520x over previous
//
#include <hip/hip_runtime.h>

#define NTOK 2048
#define IN_DIM 1024
#define OUT_DIM 512
#define RNK 32
#define TG_N 32
#define TGK_N 128
#define AWCOLS 4096
#define KD 4224          // 4096 affine_w cols + 128 bias-indicator cols
#define NKT 66           // KD / 64
#define SCALE_F 0.17677669529663687f

typedef __attribute__((ext_vector_type(8))) short short8;
typedef __attribute__((ext_vector_type(4))) float float4v;

__device__ __forceinline__ unsigned short f2bf(float f) {
  union { float f; unsigned int u; } c; c.f = f;
  unsigned int u = c.u;
  u += 0x7fffu + ((u >> 16) & 1u);   // round-to-nearest-even
  return (unsigned short)(u >> 16);
}

// Kernel 1: per-token z (bf16[32]) + winners packed 2 bits/tg into a u64.
// Scores/argmin in fp32, identical summation order to R1 (which passed).
__global__ __launch_bounds__(256) void k_zwin(
    const float* __restrict__ x, const float* __restrict__ proj_w,
    const float* __restrict__ router_w, const float* __restrict__ router_b,
    unsigned short* __restrict__ zout, unsigned long long* __restrict__ wout) {
  const int tok = blockIdx.x;
  const int t = threadIdx.x;
  __shared__ __align__(16) float zbuf[RNK];
  __shared__ float sc[TGK_N];
  __shared__ int winbuf[TG_N];

  const int r = t >> 3, c = t & 7;
  const float4* x4 = (const float4*)(x + (size_t)tok * IN_DIM);
  const float4* w4 = (const float4*)(proj_w + (size_t)r * IN_DIM);
  float acc = 0.f;
#pragma unroll
  for (int jj = 0; jj < 32; ++jj) {
    float4 xv = x4[jj * 8 + c];
    float4 wv = w4[jj * 8 + c];
    acc += xv.x * wv.x + xv.y * wv.y + xv.z * wv.z + xv.w * wv.w;
  }
  acc += __shfl_xor(acc, 1);
  acc += __shfl_xor(acc, 2);
  acc += __shfl_xor(acc, 4);
  if (c == 0) zbuf[r] = acc;
  __syncthreads();

  if (t < TGK_N) {
    const float4* rw = (const float4*)(router_w + (size_t)t * RNK);
    const float4* zb = (const float4*)zbuf;
    float s = router_b[t];
#pragma unroll
    for (int j = 0; j < 8; ++j) {
      float4 a = rw[j]; float4 b = zb[j];
      s += a.x * b.x + a.y * b.y + a.z * b.z + a.w * b.w;
    }
    sc[t] = s;
  }
  __syncthreads();

  if (t < TG_N) {
    float best = sc[t * 4]; int w = 0;
#pragma unroll
    for (int k = 1; k < 4; ++k) {
      float v = sc[t * 4 + k];
      if (v < best) { best = v; w = k; }
    }
    winbuf[t] = w;
  }
  if (t < RNK) zout[(size_t)tok * RNK + t] = f2bf(zbuf[t]);
  __syncthreads();
  if (t == 0) {
    unsigned long long w = 0ull;
    for (int g = 0; g < TG_N; ++g)
      w |= ((unsigned long long)(winbuf[g] & 3)) << (2 * g);
    wout[tok] = w;
  }
}

// Kernel 2: W2t (OUT_DIM x KD bf16) = [affine_w ; affine_b] cast + transposed.
__global__ __launch_bounds__(256) void k_w2t(
    const float* __restrict__ aw, const float* __restrict__ ab,
    unsigned short* __restrict__ w2t) {
  __shared__ float tile[32][33];
  const int c0 = blockIdx.x * 32, o0 = blockIdx.y * 32;
  const int oo = threadIdx.x & 31, cc = threadIdx.x >> 5;  // cc 0..7
#pragma unroll
  for (int p = 0; p < 4; ++p) {
    int cidx = c0 + cc + p * 8;
    float v = (cidx < AWCOLS)
                  ? aw[(size_t)cidx * OUT_DIM + o0 + oo]
                  : ab[(size_t)(cidx - AWCOLS) * OUT_DIM + o0 + oo];
    tile[cc + p * 8][oo] = v;
  }
  __syncthreads();
  const int cc2 = threadIdx.x & 31, oo2 = threadIdx.x >> 5;
#pragma unroll
  for (int p = 0; p < 4; ++p) {
    int o = o0 + oo2 + p * 8;
    w2t[(size_t)o * KD + c0 + cc2] = f2bf(tile[cc2][oo2 + p * 8]);
  }
}

// Kernel 3: out(2048x512) = Zexp @ W2t^T with Zexp built IN REGISTERS:
// A-frag = (winner(m,tg)==k) ? z[m][quad*8..+8] : 0. No A staging at all.
// 64(M) x 32(N) per block, grid 32x16 = 512 blocks (2/CU). B double-buffered
// via global_load_lds(16B), XOR-swizzled chunks; raw s_barrier + vmcnt(1)
// keeps the next tile's DMA in flight across the barrier.
__global__ __launch_bounds__(256) void k_gemm(
    const unsigned short* __restrict__ z, const unsigned long long* __restrict__ win,
    const unsigned short* __restrict__ Bt, float* __restrict__ out) {
  __shared__ __align__(16) unsigned short Bs[2][32 * 64];
  const int bm = blockIdx.x, bn = blockIdx.y;
  const int tid = threadIdx.x;
  const int wave = tid >> 6, lane = tid & 63;
  const int l15 = lane & 15, quad = lane >> 4;
  const int mw = (wave & 1) * 32;        // wave M offset
  const int nw = (wave >> 1) * 16;       // wave N offset

  // A operand: z frags + winner bits, register-resident for the whole kernel
  const int m0 = bm * 64 + mw + l15;
  const int m1 = m0 + 16;
  short8 z0 = *(const short8*)(z + (size_t)m0 * RNK + quad * 8);
  short8 z1 = *(const short8*)(z + (size_t)m1 * RNK + quad * 8);
  const unsigned long long w0 = win[m0], w1 = win[m1];

  // B staging: wave w fills rows 8w..8w+8; lane -> (row = lane>>3, chunk = lane&7)
  // source chunk XOR-swizzled by row so frag reads are 2-way (free)
  const int nloc = wave * 8 + (lane >> 3);
  const int schunk = (lane & 7) ^ ((lane >> 3) & 7);
  const unsigned short* bsrc = Bt + (size_t)(bn * 32 + nloc) * KD + schunk * 8;

  float4v acc0 = {}, acc1 = {};
  const int nb = nw + l15;               // B row (n) this lane reads
  const int nrow = nb * 64;

  // prefetch kt=0 into buf0
  __builtin_amdgcn_global_load_lds(
      (const __attribute__((address_space(1))) void*)bsrc,
      (__attribute__((address_space(3))) void*)(&Bs[0][wave * 512]), 16, 0, 0);

  for (int kt = 0; kt < NKT; ++kt) {
    if (kt + 1 < NKT) {
      __builtin_amdgcn_global_load_lds(
          (const __attribute__((address_space(1))) void*)(bsrc + (size_t)(kt + 1) * 64),
          (__attribute__((address_space(3))) void*)(&Bs[(kt + 1) & 1][wave * 512]),
          16, 0, 0);
      asm volatile("s_waitcnt vmcnt(1)" ::: "memory");  // kt landed; kt+1 in flight
    } else {
      asm volatile("s_waitcnt vmcnt(0)" ::: "memory");
    }
    asm volatile("s_barrier" ::: "memory");

    const unsigned short* B0 = &Bs[kt & 1][0];
    if (kt < 64) {
      const int tg = kt >> 1;
      const unsigned int e0 = (unsigned int)(w0 >> (2 * tg)) & 3u;
      const unsigned int e1 = (unsigned int)(w1 >> (2 * tg)) & 3u;
#pragma unroll
      for (int s = 0; s < 2; ++s) {
        const unsigned int kk = (unsigned int)(((kt & 1) << 1) | s);
        short8 zz = {};
        short8 a0 = (e0 == kk) ? z0 : zz;
        short8 a1 = (e1 == kk) ? z1 : zz;
        short8 b = *(const short8*)(B0 + nrow + (((s * 4 + quad) ^ (nb & 7)) * 8));
        acc0 = __builtin_amdgcn_mfma_f32_16x16x32_bf16(a0, b, acc0, 0, 0, 0);
        acc1 = __builtin_amdgcn_mfma_f32_16x16x32_bf16(a1, b, acc1, 0, 0, 0);
      }
    } else {
      // bias-indicator tiles: cols 4096..4223, one-hot bf16(1.0) at winner cell
#pragma unroll
      for (int s = 0; s < 2; ++s) {
        const int tgA = (kt - 64) * 16 + s * 8 + quad * 2;  // <= 30
        union { short8 v; unsigned long long q[2]; } fa, fb;
        fa.q[0] = 0x3F80ull << (((unsigned)(w0 >> (2 * tgA)) & 3u) * 16);
        fa.q[1] = 0x3F80ull << (((unsigned)(w0 >> (2 * (tgA + 1))) & 3u) * 16);
        fb.q[0] = 0x3F80ull << (((unsigned)(w1 >> (2 * tgA)) & 3u) * 16);
        fb.q[1] = 0x3F80ull << (((unsigned)(w1 >> (2 * (tgA + 1))) & 3u) * 16);
        short8 b = *(const short8*)(B0 + nrow + (((s * 4 + quad) ^ (nb & 7)) * 8));
        acc0 = __builtin_amdgcn_mfma_f32_16x16x32_bf16(fa.v, b, acc0, 0, 0, 0);
        acc1 = __builtin_amdgcn_mfma_f32_16x16x32_bf16(fb.v, b, acc1, 0, 0, 0);
      }
    }
    asm volatile("s_barrier" ::: "memory");  // all reads of this buf done before overwrite
  }

  // epilogue: C/D layout col = lane&15, row = quad*4 + reg
  const int col = bn * 32 + nw + l15;
#pragma unroll
  for (int tm = 0; tm < 2; ++tm) {
    float4v a = tm ? acc1 : acc0;
    const int rowb = bm * 64 + mw + tm * 16 + quad * 4;
#pragma unroll
    for (int rg = 0; rg < 4; ++rg)
      out[(size_t)(rowb + rg) * OUT_DIM + col] = a[rg] * SCALE_F;
  }
}

extern "C" void kernel_launch(void* const* d_in, const int* in_sizes, int n_in,
                              void* d_out, int out_size, void* d_ws, size_t ws_size,
                              hipStream_t stream) {
  const float* x        = (const float*)d_in[0];
  const float* proj_w   = (const float*)d_in[1];
  const float* router_w = (const float*)d_in[2];
  const float* router_b = (const float*)d_in[3];
  const float* affine_w = (const float*)d_in[4];
  const float* affine_b = (const float*)d_in[5];
  float* out = (float*)d_out;

  unsigned short* zout = (unsigned short*)d_ws;                       // 128 KB
  unsigned long long* wout = (unsigned long long*)((char*)d_ws + 131072);  // 16 KB
  unsigned short* w2t = (unsigned short*)((char*)d_ws + 147456);      // 4.33 MB

  k_w2t<<<dim3(KD / 32, OUT_DIM / 32), 256, 0, stream>>>(affine_w, affine_b, w2t);
  k_zwin<<<NTOK, 256, 0, stream>>>(x, proj_w, router_w, router_b, zout, wout);
  k_gemm<<<dim3(NTOK / 64, OUT_DIM / 32), 256, 0, stream>>>(zout, wout, w2t, out);
}